// Round 2
// baseline (140.028 us; speedup 1.0000x reference)
//
#include <hip/hip_runtime.h>
#include <hip/hip_bf16.h>
#include <stdint.h>

// KAN layer fused kernel, MI355X (gfx950).
// out[M=65536, N=256] (fp32) = A[M, K=256] @ W^T, where
//   A[m,k] = c0[k]*B0(tanh(x[m,k])) + c1[k]*B1(tanh(x[m,k]))  (computed on the fly -> bf16)
//   W = outer_coeffs [N,K] fp32 -> bf16 (pre-kernel into d_ws)
// B-splines: uniform knots h=2/7 on [-1,1]; u=(t+1)*3.5;
//   Bk(t) = cardinal cubic B3(u-k) = (1/6) sum_j (-1)^j C(4,j) relu(u-k-j)^3
// NOTE: d_out is FLOAT32 (reference einsum output dtype). R1 failed because we
// stored bf16 — readback as fp32 produced the observed 0.451 absmax signature.

typedef __attribute__((ext_vector_type(8))) short short8;   // 8 bf16 = 4 VGPR (MFMA A/B frag)
typedef __attribute__((ext_vector_type(4))) float f32x4;    // MFMA C/D frag

__device__ __forceinline__ uint16_t f2bf(float f) {
    union { float f; uint32_t u; } v; v.f = f;
    uint32_t r = v.u + 0x7FFFu + ((v.u >> 16) & 1u);  // RNE
    return (uint16_t)(r >> 16);
}

__device__ __forceinline__ float cube_relu(float v) {
    float m = fmaxf(v, 0.0f);
    return m * m * m;
}

__device__ __forceinline__ float inner_eval(float xx, float c0, float c1) {
    // tanh via exp: tanh(x) = 1 - 2/(e^{2x}+1); saturates correctly at +/-inf
    float e  = __expf(2.0f * xx);
    float t  = 1.0f - 2.0f * __builtin_amdgcn_rcpf(e + 1.0f);
    float u  = (t + 1.0f) * 3.5f;          // in [0,7]
    float w0 = cube_relu(u);
    float w1 = cube_relu(u - 1.0f);
    float w2 = cube_relu(u - 2.0f);
    float w3 = cube_relu(u - 3.0f);
    float w4 = cube_relu(u - 4.0f);
    float w5 = cube_relu(u - 5.0f);
    float B0 = w0 - 4.0f*w1 + 6.0f*w2 - 4.0f*w3 + w4;
    float B1 = w1 - 4.0f*w2 + 6.0f*w3 - 4.0f*w4 + w5;
    return (c0 * B0 + c1 * B1) * (1.0f / 6.0f);
}

__device__ __forceinline__ void load_lds16(const void* g, void* l) {
    __builtin_amdgcn_global_load_lds(
        (const __attribute__((address_space(1))) uint32_t*)g,
        (__attribute__((address_space(3))) uint32_t*)l, 16, 0, 0);
}

// W fp32 -> bf16, 65536 elems, 4/thread
__global__ void conv_w(const float4* __restrict__ wf, uint2* __restrict__ o) {
    const int i = blockIdx.x * blockDim.x + threadIdx.x;  // 0..16383
    const float4 v = wf[i];
    uint2 r;
    r.x = (uint32_t)f2bf(v.x) | ((uint32_t)f2bf(v.y) << 16);
    r.y = (uint32_t)f2bf(v.z) | ((uint32_t)f2bf(v.w) << 16);
    o[i] = r;
}

// Block: 256 threads (4 waves). Tile BM=64 x BN=256, BK=32, K=256 (8 iters).
// Wave w covers n in [w*64, w*64+64): 4x4 tiles of 16x16x32 MFMA.
// LDS: A[64][32] bf16 @0 (4 KB) | B[256][32] bf16 @4096 (16 KB) | coeff float2[256] @20480 (2 KB)
#define SMEM_BYTES 22528

__global__ void kan_fused(const float* __restrict__ x,
                          const float* __restrict__ ic,
                          const uint16_t* __restrict__ wb,
                          float* __restrict__ out)
{
    __shared__ __align__(16) char smem[SMEM_BYTES];
    uint16_t* A_lds  = (uint16_t*)smem;            // [64][32]
    char*     B_base = smem + 4096;                // [256][32] bf16
    float2*   C2     = (float2*)(smem + 20480);    // (c0,c1) per channel

    const int t    = threadIdx.x;
    const int lane = t & 63;
    const int w    = t >> 6;
    const int m0   = blockIdx.x * 64;

    // coeff preload: blockDim == IN == 256 (first loop-top __syncthreads covers this)
    C2[t] = make_float2(ic[t * 5 + 0], ic[t * 5 + 1]);

    f32x4 acc[4][4];
    #pragma unroll
    for (int i = 0; i < 4; ++i)
        #pragma unroll
        for (int j = 0; j < 4; ++j)
            acc[i][j] = (f32x4){0.f, 0.f, 0.f, 0.f};

    const int rowA = t >> 3;          // 0..31
    const int colA = (t & 7) << 2;    // 0..28, step 4
    const int mrow = lane & 15;
    const int quad = lane >> 4;

    #pragma unroll 1
    for (int kk = 0; kk < 8; ++kk) {
        __syncthreads();  // prev MFMA LDS reads done before restaging (also covers coeff init)

        // --- async stage W chunk [256][32] bf16 via global_load_lds (16 B/lane) ---
        // LDS dest = wave-uniform base + lane*16 (HW semantics) — layout matches exactly.
        #pragma unroll
        for (int j = 0; j < 4; ++j) {
            const int f = ((w * 4 + j) << 10) + lane * 16;  // flat byte in B_lds
            const int r = f >> 6;                           // W row (n)
            const int q = (f >> 4) & 3;                     // 16B quarter within row chunk
            load_lds16(wb + r * 256 + kk * 32 + q * 8, B_base + f);
        }

        // --- stage A chunk [64][32]: load x fp32, tanh+spline+coeff, pack bf16 ---
        #pragma unroll
        for (int j = 0; j < 2; ++j) {
            const int r  = rowA + j * 32;          // 0..63
            const int gk = kk * 32 + colA;         // global k
            const float4 xv = *(const float4*)(x + (size_t)(m0 + r) * 256 + gk);
            const float4 cA = *(const float4*)(&C2[gk]);      // c0,c1 of gk, gk+1
            const float4 cB = *(const float4*)(&C2[gk + 2]);  // c0,c1 of gk+2, gk+3
            float v0 = inner_eval(xv.x, cA.x, cA.y);
            float v1 = inner_eval(xv.y, cA.z, cA.w);
            float v2 = inner_eval(xv.z, cB.x, cB.y);
            float v3 = inner_eval(xv.w, cB.z, cB.w);
            uint32_t p0 = (uint32_t)f2bf(v0) | ((uint32_t)f2bf(v1) << 16);
            uint32_t p1 = (uint32_t)f2bf(v2) | ((uint32_t)f2bf(v3) << 16);
            *(uint2*)((char*)A_lds + (r * 32 + colA) * 2) = make_uint2(p0, p1);
        }

        __syncthreads();  // drains vmcnt (global_load_lds) + lgkm (ds_write)

        // --- MFMA phase ---
        short8 a[4], b[4];
        #pragma unroll
        for (int i = 0; i < 4; ++i) {
            // A frag: A[m = i*16+mrow][k = quad*8 + j]
            a[i] = *(const short8*)((const char*)A_lds + ((i * 16 + mrow) * 32 + quad * 8) * 2);
            // B frag: W[n = w*64 + i*16 + mrow][k = quad*8 + j]
            b[i] = *(const short8*)(B_base + ((w * 64 + i * 16 + mrow) * 32 + quad * 8) * 2);
        }
        #pragma unroll
        for (int i = 0; i < 4; ++i)
            #pragma unroll
            for (int j = 0; j < 4; ++j)
                acc[i][j] = __builtin_amdgcn_mfma_f32_16x16x32_bf16(a[i], b[j], acc[i][j], 0, 0, 0);
    }

    // --- epilogue: direct fp32 stores from accumulators ---
    // C/D layout: col = lane&15, row = quad*4 + reg  [m89/m91 verified]
    // For fixed (i,j,r): 16 consecutive floats per quad-group -> 64B fully-covered segments.
    #pragma unroll
    for (int i = 0; i < 4; ++i) {
        #pragma unroll
        for (int r = 0; r < 4; ++r) {
            const size_t row = (size_t)(m0 + i * 16 + quad * 4 + r);
            float* orow = out + row * 256 + w * 64 + mrow;
            #pragma unroll
            for (int j = 0; j < 4; ++j)
                orow[j * 16] = acc[i][j][r];
        }
    }
}

extern "C" void kernel_launch(void* const* d_in, const int* in_sizes, int n_in,
                              void* d_out, int out_size, void* d_ws, size_t ws_size,
                              hipStream_t stream) {
    const float* x  = (const float*)d_in[0];   // [16,4096,256] fp32
    const float* ic = (const float*)d_in[1];   // [256,5] fp32
    const float* oc = (const float*)d_in[2];   // [256,256] fp32
    uint16_t* wb = (uint16_t*)d_ws;            // 128 KB bf16 copy of W

    conv_w<<<64, 256, 0, stream>>>((const float4*)oc, (uint2*)wb);
    kan_fused<<<1024, 256, 0, stream>>>(x, ic, wb, (float*)d_out);
}